// Round 5
// baseline (504.242 us; speedup 1.0000x reference)
//
#include <hip/hip_runtime.h>

// Round 7: A/B revert of the round-6 GEMM ring.
//  - GEMM: back to the round-5 2-phase double-buffered loop (32 KB LDS,
//    __syncthreads with implicit drain) — the structure that measured 430 us.
//    The 3-deep counted-vmcnt ring (48 KB LDS, raw s_barrier) cost ~73 us:
//    occupancy 5->3 blocks/CU + hand-pinned schedule (m131-m141 failure mode).
//  - attn: keeps round-6 no-online-max softmax (bounded scores; masked -1e30
//    -> expf -> 0) — passed, pure VALU savings.
//  - prep: keeps the merged patchify+transpose+bias-GEMV single launch.

typedef unsigned short u16;
typedef unsigned int u32;
typedef __attribute__((ext_vector_type(8))) short bf16x8;
typedef __attribute__((ext_vector_type(4))) float f32x4;
typedef __attribute__((ext_vector_type(4))) u16 u16x4;

#define Y_ELEMS  16777216   // B*T*C = 64*256*1024
#define KV_ELEMS 16777216   // B*H*T*D

__device__ __forceinline__ u16 f2b(float f) {
  u32 u = __float_as_uint(f);
  u32 r = u + 0x7fffu + ((u >> 16) & 1u);
  return (u16)(r >> 16);
}

__device__ __forceinline__ void gl_lds16(const u16* g, u16* l) {
  __builtin_amdgcn_global_load_lds(
      (__attribute__((address_space(1))) void*)g,
      (__attribute__((address_space(3))) void*)l, 16, 0, 0);
}

// ---------------- prep: patchify + weight transposes + bias GEMV -----------
// blocks [0,4096): patchify x[64,1,256,256] -> A_patch bf16 [16384,256]
// blocks [4096,8192): transpose Wq/Wk/Wv/Wp (z = idx/1024)
// blocks [8192,8448): transpose conv_w [1024,256] -> Wc_t [256,1024]
// blocks [8448,8460): bias_f[n] = b_seg[n] + sum_c W_seg[c,n]*conv_b[c]
__global__ __launch_bounds__(256) void prep_kernel(
    const float* __restrict__ x, const float* __restrict__ conv_w,
    const float* __restrict__ conv_b,
    const float* __restrict__ Wq, const float* __restrict__ Wk,
    const float* __restrict__ Wv, const float* __restrict__ Wp,
    const float* __restrict__ bq, const float* __restrict__ bk,
    const float* __restrict__ bv,
    u16* __restrict__ ap, u16* __restrict__ Wqkv_t, u16* __restrict__ Wp_t,
    u16* __restrict__ Wc_t, float* __restrict__ bias_f) {
  __shared__ float tile[32][33];
  const int t = threadIdx.x;
  int bid = blockIdx.x;

  if (bid < 4096) {                      // ---- patchify ----
    int tid = bid * 256 + t;
    float4 v = ((const float4*)x)[tid];
    int col4 = tid & 63;
    int row  = (tid >> 6) & 255;
    int b    = tid >> 14;
    int py = row >> 4, ky = row & 15;
    int col = col4 << 2;
    int px = col >> 4, kx = col & 15;
    size_t dst = ((size_t)(b * 256 + py * 16 + px)) * 256 + ky * 16 + kx;
    u16x4 o = { f2b(v.x), f2b(v.y), f2b(v.z), f2b(v.w) };
    *(u16x4*)(ap + dst) = o;
    return;
  }
  bid -= 4096;
  if (bid < 4352) {                      // ---- transposes ----
    int z, bx, by;
    if (bid < 4096) { z = bid >> 10; int r = bid & 1023; bx = r & 31; by = r >> 5; }
    else            { z = 4; int r = bid - 4096; bx = r & 7; by = r >> 3; }
    const float* W = (z == 0) ? Wq : (z == 1) ? Wk : (z == 2) ? Wv
                   : (z == 3) ? Wp : conv_w;
    u16* dst = (z < 3) ? (Wqkv_t + (size_t)z * 1024 * 1024)
             : (z == 3) ? Wp_t : Wc_t;
    const int stride = (z == 4) ? 256 : 1024;
    int x0 = bx * 32, y0 = by * 32;
    int tx = t & 31, ty = t >> 5;
#pragma unroll
    for (int i = ty; i < 32; i += 8)
      tile[i][tx] = W[(size_t)(y0 + i) * stride + x0 + tx];
    __syncthreads();
#pragma unroll
    for (int i = ty; i < 32; i += 8)
      dst[(size_t)(x0 + i) * 1024 + y0 + tx] = f2b(tile[tx][i]);
    return;
  }
  bid -= 4352;                           // ---- bias GEMV (12 blocks) ----
  int seg = bid >> 2;
  const float* W = (seg == 0) ? Wq : (seg == 1) ? Wk : Wv;
  const float* bb = (seg == 0) ? bq : (seg == 1) ? bk : bv;
  int n = (bid & 3) * 256 + t;
  float acc = 0.f;
#pragma unroll 4
  for (int c = 0; c < 1024; ++c) acc += W[(size_t)c * 1024 + n] * conv_b[c];
  bias_f[seg * 1024 + n] = bb[n] + acc;
}

// ---------------- NT GEMM: A[M,K] bf16 row-major, Bt[N,K] bf16 row-major ---
// 2-phase pipelined main loop (double-buffered LDS).
// mode 0: O = A*B (+bias0 if non-null) -> ob0 bf16 [M,N]
// mode 1: fused qkv (N=3072, bias_f[3072]): seg0 -> q bf16 [bh,t,d] (ob0);
//         seg1/2 -> fp32 present only (of0 + (seg-1)*KV_ELEMS).
// mode 2: O = A*B + bias0 -> of0 fp32 [M,N]
__global__ __launch_bounds__(256) void gemm_kernel(
    const u16* __restrict__ A, const u16* __restrict__ Bt,
    int K, int N, int mode, const float* __restrict__ bias0,
    u16* __restrict__ ob0, float* __restrict__ of0) {
  // 4 x 8192 B (As0,Bs0,As1,Bs1); epilogue transpose reuses first 17408 B.
  __shared__ __attribute__((aligned(16))) char smem[32768];
  u16* As0 = (u16*)smem;
  u16* Bs0 = (u16*)(smem + 8192);
  u16* As1 = (u16*)(smem + 16384);
  u16* Bs1 = (u16*)(smem + 24576);
  const int t = threadIdx.x;
  const int rr = t >> 2;
  const int c8 = (t & 3) << 3;
  const int lane = t & 63;
  const int w = t >> 6;
  const int wm = (w & 1) << 6, wn = (w >> 1) << 6;
  const int l15 = lane & 15, quad = lane >> 4;
  const int tile_m = blockIdx.x * 128, tile_n = blockIdx.y * 128;

  f32x4 acc[4][4];
  f32x4 zero = {0.f, 0.f, 0.f, 0.f};
#pragma unroll
  for (int i = 0; i < 4; ++i)
#pragma unroll
    for (int j = 0; j < 4; ++j) acc[i][j] = zero;

  const u16* gA0 = A + (size_t)(tile_m + rr) * K + c8;
  const u16* gA1 = A + (size_t)(tile_m + 64 + rr) * K + c8;
  const u16* gB0 = Bt + (size_t)(tile_n + rr) * K + c8;
  const u16* gB1 = Bt + (size_t)(tile_n + 64 + rr) * K + c8;
  const int lo0 = rr * 32 + c8;          // lane-linear (t*16 bytes)
  const int lo1 = (64 + rr) * 32 + c8;

  // prologue: stage tile 0 into buf0
  gl_lds16(gA0, As0 + lo0);
  gl_lds16(gA1, As0 + lo1);
  gl_lds16(gB0, Bs0 + lo0);
  gl_lds16(gB1, Bs0 + lo1);
  __syncthreads();   // implicit vmcnt(0) drain -> tile 0 ready

  int cur = 0;
  for (int k0 = 0; k0 < K; k0 += 32, cur ^= 1) {
    u16* Asc = cur ? As1 : As0;
    u16* Bsc = cur ? Bs1 : Bs0;
    if (k0 + 32 < K) {               // issue next tile early (no wait)
      u16* Asn = cur ? As0 : As1;
      u16* Bsn = cur ? Bs0 : Bs1;
      gl_lds16(gA0 + k0 + 32, Asn + lo0);
      gl_lds16(gA1 + k0 + 32, Asn + lo1);
      gl_lds16(gB0 + k0 + 32, Bsn + lo0);
      gl_lds16(gB1 + k0 + 32, Bsn + lo1);
    }
    bf16x8 af[4], bfr[4];
#pragma unroll
    for (int i = 0; i < 4; ++i)
      af[i] = *(const bf16x8*)(Asc + (wm + 16 * i + l15) * 32 + quad * 8);
#pragma unroll
    for (int j = 0; j < 4; ++j)
      bfr[j] = *(const bf16x8*)(Bsc + (wn + 16 * j + l15) * 32 + quad * 8);
    __builtin_amdgcn_s_setprio(1);
#pragma unroll
    for (int i = 0; i < 4; ++i)
#pragma unroll
      for (int j = 0; j < 4; ++j)
        acc[i][j] = __builtin_amdgcn_mfma_f32_16x16x32_bf16(af[i], bfr[j], acc[i][j], 0, 0, 0);
    __builtin_amdgcn_s_setprio(0);
    __syncthreads();   // drains vmcnt (next tile landed) + all reads done
  }

  // ---- epilogue: per-wave LDS transpose -> vectorized stores --------------
  float* ep = (float*)smem + w * 1088;   // 16 rows x stride 68 f32 per wave
  const int ncol = wn + quad * 16;       // this lane's 16-wide column base

  f32x4 ba[4];
  if (bias0) {
#pragma unroll
    for (int cc = 0; cc < 4; ++cc)
      ba[cc] = *(const f32x4*)(bias0 + tile_n + ncol + cc * 4);
  } else {
#pragma unroll
    for (int cc = 0; cc < 4; ++cc) ba[cc] = zero;
  }

  int seg = 0, h = 0, dd = 0;
  float* pf = of0;
  if (mode == 1) {
    seg = tile_n >> 10;  // block-uniform (tile_n multiple of 128)
    pf = of0 + (size_t)(seg ? (seg - 1) : 0) * KV_ELEMS;
    int nloc = (tile_n & 1023) + ncol;
    h = nloc >> 7;
    dd = nloc & 127;
  }
  const bool need_bf = (mode == 0) || (mode == 1 && seg == 0);

#pragma unroll
  for (int i = 0; i < 4; ++i) {
    // scatter this wave's 16x64 fp32 slice into padded LDS (2-way banks, free)
#pragma unroll
    for (int j = 0; j < 4; ++j)
#pragma unroll
      for (int r = 0; r < 4; ++r)
        ep[(quad * 4 + r) * 68 + j * 16 + l15] = acc[i][j][r];
    asm volatile("s_waitcnt lgkmcnt(0)" ::: "memory");  // wave-local RAW
    f32x4 vt[4];
#pragma unroll
    for (int cc = 0; cc < 4; ++cc) {
      vt[cc] = *(const f32x4*)(ep + l15 * 68 + quad * 16 + cc * 4);
      vt[cc] += ba[cc];
    }
    asm volatile("s_waitcnt lgkmcnt(0)" ::: "memory");  // reads done before next i
    const int m = tile_m + wm + 16 * i + l15;

    bf16x8 h0, h1;
    if (need_bf) {
#pragma unroll
      for (int e = 0; e < 8; ++e) h0[e] = (short)f2b(vt[e >> 2][e & 3]);
#pragma unroll
      for (int e = 0; e < 8; ++e) h1[e] = (short)f2b(vt[2 + (e >> 2)][e & 3]);
    }

    if (mode == 1) {
      int bb = m >> 8, tt = m & 255;
      size_t idx = ((size_t)(bb * 8 + h) * 256 + tt) * 128 + dd;
      if (seg == 0) {
        *(bf16x8*)(ob0 + idx) = h0;
        *(bf16x8*)(ob0 + idx + 8) = h1;
      } else {
#pragma unroll
        for (int cc = 0; cc < 4; ++cc) *(f32x4*)(pf + idx + cc * 4) = vt[cc];
      }
    } else if (mode == 2) {
      float* p = of0 + (size_t)m * N + tile_n + ncol;
#pragma unroll
      for (int cc = 0; cc < 4; ++cc) *(f32x4*)(p + cc * 4) = vt[cc];
    } else {  // mode 0: bf16 [M,N]
      u16* p = ob0 + (size_t)m * N + tile_n + ncol;
      *(bf16x8*)p = h0;
      *(bf16x8*)(p + 8) = h1;
    }
  }
}

// ---------------- flash attention: 2048 blocks (XCD-swizzled), 4 waves -----
// No online-max: scores are bounded (|s| small), masked entries are -1e30 ->
// expf underflows to 0. li accumulates plain exp sums. K/V staged from fp32
// `present` with in-register f2b.
__global__ __launch_bounds__(256) void attn_kernel(
    const u16* __restrict__ qw, const float* __restrict__ kf,
    const float* __restrict__ vf, u16* __restrict__ yatt) {
  __shared__ __attribute__((aligned(16))) u16 Ks[64 * 136];   // rows padded +8
  __shared__ __attribute__((aligned(16))) u16 Vs[128 * 72];   // [d][j], padded
  __shared__ __attribute__((aligned(16))) u16 Ps[4 * 16 * 72];
  // XCD-aware decode: the 4 qb-blocks of one bh land on the same XCD.
  const int id = blockIdx.x;
  const int xr = id & 7;
  const int kk = id >> 3;
  const int qb = kk & 3;
  const int bh = ((kk >> 2) << 3) + xr;
  const int t = threadIdx.x;
  const int lane = t & 63, w = t >> 6;
  const int l15 = lane & 15, quad = lane >> 4;
  const int qrow0 = qb * 64 + w * 16;

  bf16x8 aq[4];
#pragma unroll
  for (int ks = 0; ks < 4; ++ks)
    aq[ks] = *(const bf16x8*)(qw + ((size_t)bh * 256 + qrow0 + l15) * 128 + ks * 32 + quad * 8);

  f32x4 o[8];
  f32x4 zero = {0.f, 0.f, 0.f, 0.f};
#pragma unroll
  for (int dt = 0; dt < 8; ++dt) o[dt] = zero;
  float li[4] = {0.f, 0.f, 0.f, 0.f};

  const int jp = (t & 31) * 2;    // V staging: row pair within the 64-tile
  const int db = (t >> 5) * 16;   // V staging: 16 d values
  const int kr = t >> 2, kc = t & 3;
  const float* kbase = kf + (size_t)bh * 256 * 128;
  const float* vbase = vf + (size_t)bh * 256 * 128;

  for (int j = 0; j <= qb; ++j) {
    __syncthreads();
    {
      const float* ksrc = kbase + (size_t)j * 64 * 128;
#pragma unroll
      for (int s = 0; s < 4; ++s) {
        const float* p = ksrc + (size_t)kr * 128 + (s * 4 + kc) * 8;
        f32x4 a = *(const f32x4*)p;
        f32x4 b = *(const f32x4*)(p + 4);
        bf16x8 wv;
#pragma unroll
        for (int e = 0; e < 4; ++e) wv[e] = (short)f2b(a[e]);
#pragma unroll
        for (int e = 0; e < 4; ++e) wv[4 + e] = (short)f2b(b[e]);
        *(bf16x8*)(Ks + kr * 136 + (s * 4 + kc) * 8) = wv;
      }
      const float* vsrc = vbase + (size_t)j * 64 * 128;
      f32x4 v0[4], v1[4];
#pragma unroll
      for (int cc = 0; cc < 4; ++cc) {
        v0[cc] = *(const f32x4*)(vsrc + (size_t)jp * 128 + db + cc * 4);
        v1[cc] = *(const f32x4*)(vsrc + (size_t)(jp + 1) * 128 + db + cc * 4);
      }
#pragma unroll
      for (int cc = 0; cc < 4; ++cc)
#pragma unroll
        for (int e = 0; e < 4; ++e) {
          u32 p = (u32)f2b(v0[cc][e]) | ((u32)f2b(v1[cc][e]) << 16);
          *(u32*)(Vs + (db + cc * 4 + e) * 72 + jp) = p;
        }
    }
    __syncthreads();

    f32x4 s4[4];
#pragma unroll
    for (int nt = 0; nt < 4; ++nt) s4[nt] = zero;
    __builtin_amdgcn_s_setprio(1);
#pragma unroll
    for (int nt = 0; nt < 4; ++nt)
#pragma unroll
      for (int ks = 0; ks < 4; ++ks) {
        bf16x8 bk8 = *(const bf16x8*)(Ks + (nt * 16 + l15) * 136 + ks * 32 + quad * 8);
        s4[nt] = __builtin_amdgcn_mfma_f32_16x16x32_bf16(aq[ks], bk8, s4[nt], 0, 0, 0);
      }
    __builtin_amdgcn_s_setprio(0);

    const float sc = 0.08838834764831845f;  // 1/sqrt(128)
    const bool diag = (j == qb);
#pragma unroll
    for (int nt = 0; nt < 4; ++nt) {
      int coln = j * 64 + nt * 16 + l15;
#pragma unroll
      for (int r = 0; r < 4; ++r) {
        float sv = s4[nt][r] * sc;
        if (diag && coln > (qrow0 + quad * 4 + r)) sv = -1e30f;
        s4[nt][r] = sv;
      }
    }

    // softmax numerator without max-subtraction (bounded scores)
#pragma unroll
    for (int r = 0; r < 4; ++r) {
      float sum = 0.f;
#pragma unroll
      for (int nt = 0; nt < 4; ++nt) {
        float p = __expf(s4[nt][r]);
        s4[nt][r] = p;
        sum += p;
      }
#pragma unroll
      for (int off = 1; off < 16; off <<= 1)
        sum += __shfl_xor(sum, off, 64);
      li[r] += sum;
    }

    // P (C-layout fp32) -> per-wave LDS -> A-operand bf16 frags
    u16* pw = Ps + w * 16 * 72;
#pragma unroll
    for (int nt = 0; nt < 4; ++nt)
#pragma unroll
      for (int r = 0; r < 4; ++r)
        pw[(quad * 4 + r) * 72 + nt * 16 + l15] = f2b(s4[nt][r]);
    asm volatile("s_waitcnt lgkmcnt(0)" ::: "memory");  // wave-local LDS RAW

    bf16x8 ap[2];
#pragma unroll
    for (int k2 = 0; k2 < 2; ++k2)
      ap[k2] = *(const bf16x8*)(pw + l15 * 72 + k2 * 32 + quad * 8);
    __builtin_amdgcn_s_setprio(1);
#pragma unroll
    for (int dt = 0; dt < 8; ++dt)
#pragma unroll
      for (int k2 = 0; k2 < 2; ++k2) {
        bf16x8 bv8 = *(const bf16x8*)(Vs + (dt * 16 + l15) * 72 + k2 * 32 + quad * 8);
        o[dt] = __builtin_amdgcn_mfma_f32_16x16x32_bf16(ap[k2], bv8, o[dt], 0, 0, 0);
      }
    __builtin_amdgcn_s_setprio(0);
  }

  const int b = bh >> 3, h = bh & 7;
#pragma unroll
  for (int r = 0; r < 4; ++r) {
    float inv = 1.0f / li[r];
    int tt = qrow0 + quad * 4 + r;
    size_t rowbase = ((size_t)b * 256 + tt) * 1024 + h * 128;
#pragma unroll
    for (int dt = 0; dt < 8; ++dt)
      yatt[rowbase + dt * 16 + l15] = f2b(o[dt][r] * inv);
  }
}

extern "C" void kernel_launch(void* const* d_in, const int* in_sizes, int n_in,
                              void* d_out, int out_size, void* d_ws, size_t ws_size,
                              hipStream_t stream) {
  const float* x      = (const float*)d_in[0];
  const float* conv_w = (const float*)d_in[1];
  const float* conv_b = (const float*)d_in[2];
  const float* Wq     = (const float*)d_in[3];
  const float* bq     = (const float*)d_in[4];
  const float* Wk     = (const float*)d_in[5];
  const float* bk     = (const float*)d_in[6];
  const float* Wv     = (const float*)d_in[7];
  const float* bv     = (const float*)d_in[8];
  const float* Wp     = (const float*)d_in[9];
  const float* bp     = (const float*)d_in[10];
  float* out = (float*)d_out;

  char* ws = (char*)d_ws;
  // region0 [0, 32MB): precompute buffers, dead after QKV; reused as y_att.
  u16*   A_patch = (u16*)(ws);                                   // 8 MB
  u16*   Wc_t    = (u16*)(ws + (8u << 20));                      // 0.5 MB
  u16*   W2      = (u16*)(ws + (8u << 20) + (1u << 19));         // 1.5 MB
  float* bias_f  = (float*)(ws + (10u << 20));                   // 12 KB
  u16*   Wqkv_t  = (u16*)(ws + (10u << 20) + (1u << 16));        // 6 MB
  u16*   y_att   = (u16*)(ws);                                   // 32 MB alias
  u16*   Wp_t    = (u16*)(ws + (32u << 20));                     // 2 MB
  u16*   q_ws    = (u16*)(ws + (34u << 20));                     // 32 MB -> 66 MB

  float* present_k = out + Y_ELEMS;              // fp32 [64,8,256,128]
  float* present_v = out + Y_ELEMS + KV_ELEMS;

  // one prep launch: patchify(4096) + transposes(4352) + bias GEMV(12)
  prep_kernel<<<8460, 256, 0, stream>>>(
      x, conv_w, conv_b, Wq, Wk, Wv, Wp, bq, bk, bv,
      A_patch, Wqkv_t, Wp_t, Wc_t, bias_f);
  // W2[n,k] = sum_c Wqkv_t[n,c] * Wc_t[k,c]  (3072x256, K=1024)
  gemm_kernel<<<dim3(24, 2), 256, 0, stream>>>(
      Wqkv_t, Wc_t, 1024, 256, 0, nullptr, W2, nullptr);
  // fused QKV: A_patch[16384,256] x W2[3072,256]^T + bias_f, K=256
  gemm_kernel<<<dim3(128, 24), 256, 0, stream>>>(
      A_patch, W2, 256, 3072, 1, bias_f, q_ws, out + Y_ELEMS);
  attn_kernel<<<2048, 256, 0, stream>>>(q_ws, present_k, present_v, y_att);
  gemm_kernel<<<dim3(128, 8), 256, 0, stream>>>(
      y_att, Wp_t, 1024, 1024, 2, bp, nullptr, out);
}

// Round 7
// 422.456 us; speedup vs baseline: 1.1936x; 1.1936x over previous
//
#include <hip/hip_runtime.h>

// Round 8 (resubmit — round-6 bench was an infra failure, no data):
// fix the round-4/5 regression — it was prep's 12-block bias-GEMV tail
// (1024 serial HBM-latency column loads on a near-empty GPU ~60+ us),
// NOT the GEMM ring. Restore round-3's bias_fold (768 blocks, coalesced bf16
// row-dot over Wqkv_t) as its own launch after the transposes.
//  - prep: patchify + 5 transposes only (8448 blocks, no straggler tail).
//  - GEMM: round-3/5 2-phase double-buffered loop (the 430-us structure).
//  - attn: keeps no-online-max softmax (bounded scores; masked -1e30 ->
//    expf -> 0) — the single deliberate deviation from round 3.

typedef unsigned short u16;
typedef unsigned int u32;
typedef __attribute__((ext_vector_type(8))) short bf16x8;
typedef __attribute__((ext_vector_type(4))) float f32x4;
typedef __attribute__((ext_vector_type(4))) u16 u16x4;

#define Y_ELEMS  16777216   // B*T*C = 64*256*1024
#define KV_ELEMS 16777216   // B*H*T*D

__device__ __forceinline__ u16 f2b(float f) {
  u32 u = __float_as_uint(f);
  u32 r = u + 0x7fffu + ((u >> 16) & 1u);
  return (u16)(r >> 16);
}

__device__ __forceinline__ float b2f(u16 h) {
  return __uint_as_float(((u32)h) << 16);
}

__device__ __forceinline__ void gl_lds16(const u16* g, u16* l) {
  __builtin_amdgcn_global_load_lds(
      (__attribute__((address_space(1))) void*)g,
      (__attribute__((address_space(3))) void*)l, 16, 0, 0);
}

// ---------------- prep: patchify + weight transposes -----------------------
// blocks [0,4096): patchify x[64,1,256,256] -> A_patch bf16 [16384,256]
// blocks [4096,8192): transpose Wq/Wk/Wv/Wp (z = idx/1024)
// blocks [8192,8448): transpose conv_w [1024,256] -> Wc_t [256,1024]
__global__ __launch_bounds__(256) void prep_kernel(
    const float* __restrict__ x, const float* __restrict__ conv_w,
    const float* __restrict__ Wq, const float* __restrict__ Wk,
    const float* __restrict__ Wv, const float* __restrict__ Wp,
    u16* __restrict__ ap, u16* __restrict__ Wqkv_t, u16* __restrict__ Wp_t,
    u16* __restrict__ Wc_t) {
  __shared__ float tile[32][33];
  const int t = threadIdx.x;
  int bid = blockIdx.x;

  if (bid < 4096) {                      // ---- patchify ----
    int tid = bid * 256 + t;
    float4 v = ((const float4*)x)[tid];
    int col4 = tid & 63;
    int row  = (tid >> 6) & 255;
    int b    = tid >> 14;
    int py = row >> 4, ky = row & 15;
    int col = col4 << 2;
    int px = col >> 4, kx = col & 15;
    size_t dst = ((size_t)(b * 256 + py * 16 + px)) * 256 + ky * 16 + kx;
    u16x4 o = { f2b(v.x), f2b(v.y), f2b(v.z), f2b(v.w) };
    *(u16x4*)(ap + dst) = o;
    return;
  }
  bid -= 4096;
  // ---- transposes ----
  int z, bx, by;
  if (bid < 4096) { z = bid >> 10; int r = bid & 1023; bx = r & 31; by = r >> 5; }
  else            { z = 4; int r = bid - 4096; bx = r & 7; by = r >> 3; }
  const float* W = (z == 0) ? Wq : (z == 1) ? Wk : (z == 2) ? Wv
                 : (z == 3) ? Wp : conv_w;
  u16* dst = (z < 3) ? (Wqkv_t + (size_t)z * 1024 * 1024)
           : (z == 3) ? Wp_t : Wc_t;
  const int stride = (z == 4) ? 256 : 1024;
  int x0 = bx * 32, y0 = by * 32;
  int tx = t & 31, ty = t >> 5;
#pragma unroll
  for (int i = ty; i < 32; i += 8)
    tile[i][tx] = W[(size_t)(y0 + i) * stride + x0 + tx];
  __syncthreads();
#pragma unroll
  for (int i = ty; i < 32; i += 8)
    dst[(size_t)(x0 + i) * 1024 + y0 + tx] = f2b(tile[tx][i]);
}

// ---------------- folded bias: bias_f[n] = b_seg[n&1023] + <Wqkv_t[n,:], conv_b>
// 768 blocks x 4 waves; each wave: one n via coalesced 2 KB row read.
__global__ __launch_bounds__(256) void bias_fold_kernel(
    const u16* __restrict__ Wqkv_t, const float* __restrict__ conv_b,
    const float* __restrict__ bq, const float* __restrict__ bk,
    const float* __restrict__ bv, float* __restrict__ bias_f) {
  int lane = threadIdx.x & 63, w = threadIdx.x >> 6;
  int n = blockIdx.x * 4 + w;
  const u16* row = Wqkv_t + (size_t)n * 1024 + lane * 16;
  const float* cb = conv_b + lane * 16;
  bf16x8 a0 = *(const bf16x8*)row;
  bf16x8 a1 = *(const bf16x8*)(row + 8);
  float s = 0.f;
#pragma unroll
  for (int e = 0; e < 8; ++e) s += b2f((u16)a0[e]) * cb[e];
#pragma unroll
  for (int e = 0; e < 8; ++e) s += b2f((u16)a1[e]) * cb[8 + e];
#pragma unroll
  for (int off = 1; off < 64; off <<= 1) s += __shfl_xor(s, off, 64);
  if (lane == 0) {
    int seg = n >> 10, j = n & 1023;
    float base = (seg == 0 ? bq : seg == 1 ? bk : bv)[j];
    bias_f[n] = base + s;
  }
}

// ---------------- NT GEMM: A[M,K] bf16 row-major, Bt[N,K] bf16 row-major ---
// 2-phase pipelined main loop (double-buffered LDS).
// mode 0: O = A*B (+bias0 if non-null) -> ob0 bf16 [M,N]
// mode 1: fused qkv (N=3072, bias_f[3072]): seg0 -> q bf16 [bh,t,d] (ob0);
//         seg1/2 -> fp32 present only (of0 + (seg-1)*KV_ELEMS).
// mode 2: O = A*B + bias0 -> of0 fp32 [M,N]
__global__ __launch_bounds__(256) void gemm_kernel(
    const u16* __restrict__ A, const u16* __restrict__ Bt,
    int K, int N, int mode, const float* __restrict__ bias0,
    u16* __restrict__ ob0, float* __restrict__ of0) {
  // 4 x 8192 B (As0,Bs0,As1,Bs1); epilogue transpose reuses first 17408 B.
  __shared__ __attribute__((aligned(16))) char smem[32768];
  u16* As0 = (u16*)smem;
  u16* Bs0 = (u16*)(smem + 8192);
  u16* As1 = (u16*)(smem + 16384);
  u16* Bs1 = (u16*)(smem + 24576);
  const int t = threadIdx.x;
  const int rr = t >> 2;
  const int c8 = (t & 3) << 3;
  const int lane = t & 63;
  const int w = t >> 6;
  const int wm = (w & 1) << 6, wn = (w >> 1) << 6;
  const int l15 = lane & 15, quad = lane >> 4;
  const int tile_m = blockIdx.x * 128, tile_n = blockIdx.y * 128;

  f32x4 acc[4][4];
  f32x4 zero = {0.f, 0.f, 0.f, 0.f};
#pragma unroll
  for (int i = 0; i < 4; ++i)
#pragma unroll
    for (int j = 0; j < 4; ++j) acc[i][j] = zero;

  const u16* gA0 = A + (size_t)(tile_m + rr) * K + c8;
  const u16* gA1 = A + (size_t)(tile_m + 64 + rr) * K + c8;
  const u16* gB0 = Bt + (size_t)(tile_n + rr) * K + c8;
  const u16* gB1 = Bt + (size_t)(tile_n + 64 + rr) * K + c8;
  const int lo0 = rr * 32 + c8;          // lane-linear (t*16 bytes)
  const int lo1 = (64 + rr) * 32 + c8;

  // prologue: stage tile 0 into buf0
  gl_lds16(gA0, As0 + lo0);
  gl_lds16(gA1, As0 + lo1);
  gl_lds16(gB0, Bs0 + lo0);
  gl_lds16(gB1, Bs0 + lo1);
  __syncthreads();   // implicit vmcnt(0) drain -> tile 0 ready

  int cur = 0;
  for (int k0 = 0; k0 < K; k0 += 32, cur ^= 1) {
    u16* Asc = cur ? As1 : As0;
    u16* Bsc = cur ? Bs1 : Bs0;
    if (k0 + 32 < K) {               // issue next tile early (no wait)
      u16* Asn = cur ? As0 : As1;
      u16* Bsn = cur ? Bs0 : Bs1;
      gl_lds16(gA0 + k0 + 32, Asn + lo0);
      gl_lds16(gA1 + k0 + 32, Asn + lo1);
      gl_lds16(gB0 + k0 + 32, Bsn + lo0);
      gl_lds16(gB1 + k0 + 32, Bsn + lo1);
    }
    bf16x8 af[4], bfr[4];
#pragma unroll
    for (int i = 0; i < 4; ++i)
      af[i] = *(const bf16x8*)(Asc + (wm + 16 * i + l15) * 32 + quad * 8);
#pragma unroll
    for (int j = 0; j < 4; ++j)
      bfr[j] = *(const bf16x8*)(Bsc + (wn + 16 * j + l15) * 32 + quad * 8);
    __builtin_amdgcn_s_setprio(1);
#pragma unroll
    for (int i = 0; i < 4; ++i)
#pragma unroll
      for (int j = 0; j < 4; ++j)
        acc[i][j] = __builtin_amdgcn_mfma_f32_16x16x32_bf16(af[i], bfr[j], acc[i][j], 0, 0, 0);
    __builtin_amdgcn_s_setprio(0);
    __syncthreads();   // drains vmcnt (next tile landed) + all reads done
  }

  // ---- epilogue: per-wave LDS transpose -> vectorized stores --------------
  float* ep = (float*)smem + w * 1088;   // 16 rows x stride 68 f32 per wave
  const int ncol = wn + quad * 16;       // this lane's 16-wide column base

  f32x4 ba[4];
  if (bias0) {
#pragma unroll
    for (int cc = 0; cc < 4; ++cc)
      ba[cc] = *(const f32x4*)(bias0 + tile_n + ncol + cc * 4);
  } else {
#pragma unroll
    for (int cc = 0; cc < 4; ++cc) ba[cc] = zero;
  }

  int seg = 0, h = 0, dd = 0;
  float* pf = of0;
  if (mode == 1) {
    seg = tile_n >> 10;  // block-uniform (tile_n multiple of 128)
    pf = of0 + (size_t)(seg ? (seg - 1) : 0) * KV_ELEMS;
    int nloc = (tile_n & 1023) + ncol;
    h = nloc >> 7;
    dd = nloc & 127;
  }
  const bool need_bf = (mode == 0) || (mode == 1 && seg == 0);

#pragma unroll
  for (int i = 0; i < 4; ++i) {
    // scatter this wave's 16x64 fp32 slice into padded LDS (2-way banks, free)
#pragma unroll
    for (int j = 0; j < 4; ++j)
#pragma unroll
      for (int r = 0; r < 4; ++r)
        ep[(quad * 4 + r) * 68 + j * 16 + l15] = acc[i][j][r];
    asm volatile("s_waitcnt lgkmcnt(0)" ::: "memory");  // wave-local RAW
    f32x4 vt[4];
#pragma unroll
    for (int cc = 0; cc < 4; ++cc) {
      vt[cc] = *(const f32x4*)(ep + l15 * 68 + quad * 16 + cc * 4);
      vt[cc] += ba[cc];
    }
    asm volatile("s_waitcnt lgkmcnt(0)" ::: "memory");  // reads done before next i
    const int m = tile_m + wm + 16 * i + l15;

    bf16x8 h0, h1;
    if (need_bf) {
#pragma unroll
      for (int e = 0; e < 8; ++e) h0[e] = (short)f2b(vt[e >> 2][e & 3]);
#pragma unroll
      for (int e = 0; e < 8; ++e) h1[e] = (short)f2b(vt[2 + (e >> 2)][e & 3]);
    }

    if (mode == 1) {
      int bb = m >> 8, tt = m & 255;
      size_t idx = ((size_t)(bb * 8 + h) * 256 + tt) * 128 + dd;
      if (seg == 0) {
        *(bf16x8*)(ob0 + idx) = h0;
        *(bf16x8*)(ob0 + idx + 8) = h1;
      } else {
#pragma unroll
        for (int cc = 0; cc < 4; ++cc) *(f32x4*)(pf + idx + cc * 4) = vt[cc];
      }
    } else if (mode == 2) {
      float* p = of0 + (size_t)m * N + tile_n + ncol;
#pragma unroll
      for (int cc = 0; cc < 4; ++cc) *(f32x4*)(p + cc * 4) = vt[cc];
    } else {  // mode 0: bf16 [M,N]
      u16* p = ob0 + (size_t)m * N + tile_n + ncol;
      *(bf16x8*)p = h0;
      *(bf16x8*)(p + 8) = h1;
    }
  }
}

// ---------------- flash attention: 2048 blocks (XCD-swizzled), 4 waves -----
// No online-max: scores are bounded (|s| small), masked entries are -1e30 ->
// expf underflows to 0. li accumulates plain exp sums. K/V staged from fp32
// `present` with in-register f2b.
__global__ __launch_bounds__(256) void attn_kernel(
    const u16* __restrict__ qw, const float* __restrict__ kf,
    const float* __restrict__ vf, u16* __restrict__ yatt) {
  __shared__ __attribute__((aligned(16))) u16 Ks[64 * 136];   // rows padded +8
  __shared__ __attribute__((aligned(16))) u16 Vs[128 * 72];   // [d][j], padded
  __shared__ __attribute__((aligned(16))) u16 Ps[4 * 16 * 72];
  // XCD-aware decode: the 4 qb-blocks of one bh land on the same XCD.
  const int id = blockIdx.x;
  const int xr = id & 7;
  const int kk = id >> 3;
  const int qb = kk & 3;
  const int bh = ((kk >> 2) << 3) + xr;
  const int t = threadIdx.x;
  const int lane = t & 63, w = t >> 6;
  const int l15 = lane & 15, quad = lane >> 4;
  const int qrow0 = qb * 64 + w * 16;

  bf16x8 aq[4];
#pragma unroll
  for (int ks = 0; ks < 4; ++ks)
    aq[ks] = *(const bf16x8*)(qw + ((size_t)bh * 256 + qrow0 + l15) * 128 + ks * 32 + quad * 8);

  f32x4 o[8];
  f32x4 zero = {0.f, 0.f, 0.f, 0.f};
#pragma unroll
  for (int dt = 0; dt < 8; ++dt) o[dt] = zero;
  float li[4] = {0.f, 0.f, 0.f, 0.f};

  const int jp = (t & 31) * 2;    // V staging: row pair within the 64-tile
  const int db = (t >> 5) * 16;   // V staging: 16 d values
  const int kr = t >> 2, kc = t & 3;
  const float* kbase = kf + (size_t)bh * 256 * 128;
  const float* vbase = vf + (size_t)bh * 256 * 128;

  for (int j = 0; j <= qb; ++j) {
    __syncthreads();
    {
      const float* ksrc = kbase + (size_t)j * 64 * 128;
#pragma unroll
      for (int s = 0; s < 4; ++s) {
        const float* p = ksrc + (size_t)kr * 128 + (s * 4 + kc) * 8;
        f32x4 a = *(const f32x4*)p;
        f32x4 b = *(const f32x4*)(p + 4);
        bf16x8 wv;
#pragma unroll
        for (int e = 0; e < 4; ++e) wv[e] = (short)f2b(a[e]);
#pragma unroll
        for (int e = 0; e < 4; ++e) wv[4 + e] = (short)f2b(b[e]);
        *(bf16x8*)(Ks + kr * 136 + (s * 4 + kc) * 8) = wv;
      }
      const float* vsrc = vbase + (size_t)j * 64 * 128;
      f32x4 v0[4], v1[4];
#pragma unroll
      for (int cc = 0; cc < 4; ++cc) {
        v0[cc] = *(const f32x4*)(vsrc + (size_t)jp * 128 + db + cc * 4);
        v1[cc] = *(const f32x4*)(vsrc + (size_t)(jp + 1) * 128 + db + cc * 4);
      }
#pragma unroll
      for (int cc = 0; cc < 4; ++cc)
#pragma unroll
        for (int e = 0; e < 4; ++e) {
          u32 p = (u32)f2b(v0[cc][e]) | ((u32)f2b(v1[cc][e]) << 16);
          *(u32*)(Vs + (db + cc * 4 + e) * 72 + jp) = p;
        }
    }
    __syncthreads();

    f32x4 s4[4];
#pragma unroll
    for (int nt = 0; nt < 4; ++nt) s4[nt] = zero;
    __builtin_amdgcn_s_setprio(1);
#pragma unroll
    for (int nt = 0; nt < 4; ++nt)
#pragma unroll
      for (int ks = 0; ks < 4; ++ks) {
        bf16x8 bk8 = *(const bf16x8*)(Ks + (nt * 16 + l15) * 136 + ks * 32 + quad * 8);
        s4[nt] = __builtin_amdgcn_mfma_f32_16x16x32_bf16(aq[ks], bk8, s4[nt], 0, 0, 0);
      }
    __builtin_amdgcn_s_setprio(0);

    const float sc = 0.08838834764831845f;  // 1/sqrt(128)
    const bool diag = (j == qb);
#pragma unroll
    for (int nt = 0; nt < 4; ++nt) {
      int coln = j * 64 + nt * 16 + l15;
#pragma unroll
      for (int r = 0; r < 4; ++r) {
        float sv = s4[nt][r] * sc;
        if (diag && coln > (qrow0 + quad * 4 + r)) sv = -1e30f;
        s4[nt][r] = sv;
      }
    }

    // softmax numerator without max-subtraction (bounded scores)
#pragma unroll
    for (int r = 0; r < 4; ++r) {
      float sum = 0.f;
#pragma unroll
      for (int nt = 0; nt < 4; ++nt) {
        float p = __expf(s4[nt][r]);
        s4[nt][r] = p;
        sum += p;
      }
#pragma unroll
      for (int off = 1; off < 16; off <<= 1)
        sum += __shfl_xor(sum, off, 64);
      li[r] += sum;
    }

    // P (C-layout fp32) -> per-wave LDS -> A-operand bf16 frags
    u16* pw = Ps + w * 16 * 72;
#pragma unroll
    for (int nt = 0; nt < 4; ++nt)
#pragma unroll
      for (int r = 0; r < 4; ++r)
        pw[(quad * 4 + r) * 72 + nt * 16 + l15] = f2b(s4[nt][r]);
    asm volatile("s_waitcnt lgkmcnt(0)" ::: "memory");  // wave-local LDS RAW

    bf16x8 ap[2];
#pragma unroll
    for (int k2 = 0; k2 < 2; ++k2)
      ap[k2] = *(const bf16x8*)(pw + l15 * 72 + k2 * 32 + quad * 8);
    __builtin_amdgcn_s_setprio(1);
#pragma unroll
    for (int dt = 0; dt < 8; ++dt)
#pragma unroll
      for (int k2 = 0; k2 < 2; ++k2) {
        bf16x8 bv8 = *(const bf16x8*)(Vs + (dt * 16 + l15) * 72 + k2 * 32 + quad * 8);
        o[dt] = __builtin_amdgcn_mfma_f32_16x16x32_bf16(ap[k2], bv8, o[dt], 0, 0, 0);
      }
    __builtin_amdgcn_s_setprio(0);
  }

  const int b = bh >> 3, h = bh & 7;
#pragma unroll
  for (int r = 0; r < 4; ++r) {
    float inv = 1.0f / li[r];
    int tt = qrow0 + quad * 4 + r;
    size_t rowbase = ((size_t)b * 256 + tt) * 1024 + h * 128;
#pragma unroll
    for (int dt = 0; dt < 8; ++dt)
      yatt[rowbase + dt * 16 + l15] = f2b(o[dt][r] * inv);
  }
}

extern "C" void kernel_launch(void* const* d_in, const int* in_sizes, int n_in,
                              void* d_out, int out_size, void* d_ws, size_t ws_size,
                              hipStream_t stream) {
  const float* x      = (const float*)d_in[0];
  const float* conv_w = (const float*)d_in[1];
  const float* conv_b = (const float*)d_in[2];
  const float* Wq     = (const float*)d_in[3];
  const float* bq     = (const float*)d_in[4];
  const float* Wk     = (const float*)d_in[5];
  const float* bk     = (const float*)d_in[6];
  const float* Wv     = (const float*)d_in[7];
  const float* bv     = (const float*)d_in[8];
  const float* Wp     = (const float*)d_in[9];
  const float* bp     = (const float*)d_in[10];
  float* out = (float*)d_out;

  char* ws = (char*)d_ws;
  // region0 [0, 32MB): precompute buffers, dead after QKV; reused as y_att.
  u16*   A_patch = (u16*)(ws);                                   // 8 MB
  u16*   Wc_t    = (u16*)(ws + (8u << 20));                      // 0.5 MB
  u16*   W2      = (u16*)(ws + (8u << 20) + (1u << 19));         // 1.5 MB
  float* bias_f  = (float*)(ws + (10u << 20));                   // 12 KB
  u16*   Wqkv_t  = (u16*)(ws + (10u << 20) + (1u << 16));        // 6 MB
  u16*   y_att   = (u16*)(ws);                                   // 32 MB alias
  u16*   Wp_t    = (u16*)(ws + (32u << 20));                     // 2 MB
  u16*   q_ws    = (u16*)(ws + (34u << 20));                     // 32 MB -> 66 MB

  float* present_k = out + Y_ELEMS;              // fp32 [64,8,256,128]
  float* present_v = out + Y_ELEMS + KV_ELEMS;

  // prep: patchify(4096) + transposes(4352); no straggler tail
  prep_kernel<<<8448, 256, 0, stream>>>(
      x, conv_w, Wq, Wk, Wv, Wp, A_patch, Wqkv_t, Wp_t, Wc_t);
  // bias fold: 768 blocks, coalesced bf16 row-dot (round-3 structure)
  bias_fold_kernel<<<768, 256, 0, stream>>>(
      Wqkv_t, conv_b, bq, bk, bv, bias_f);
  // W2[n,k] = sum_c Wqkv_t[n,c] * Wc_t[k,c]  (3072x256, K=1024)
  gemm_kernel<<<dim3(24, 2), 256, 0, stream>>>(
      Wqkv_t, Wc_t, 1024, 256, 0, nullptr, W2, nullptr);
  // fused QKV: A_patch[16384,256] x W2[3072,256]^T + bias_f, K=256
  gemm_kernel<<<dim3(128, 24), 256, 0, stream>>>(
      A_patch, W2, 256, 3072, 1, bias_f, q_ws, out + Y_ELEMS);
  attn_kernel<<<2048, 256, 0, stream>>>(q_ws, present_k, present_v, y_att);
  gemm_kernel<<<dim3(128, 8), 256, 0, stream>>>(
      y_att, Wp_t, 1024, 1024, 2, bp, nullptr, out);
}